// Round 9
// baseline (1390.696 us; speedup 1.0000x reference)
//
#include <hip/hip_runtime.h>
#include <math.h>

#define N_TOK 8192
#define HD    1024
#define CTXD  64
#define POS_D 32
#define DG    1120
#define HID   3072
#define NE    8
#define CAP   2048
#define NK    (N_TOK * 2)
#define CH    2048          // context hidden width (2*H)

typedef _Float16 half8 __attribute__((ext_vector_type(8)));
typedef float    floatx4 __attribute__((ext_vector_type(4)));

__device__ static inline void gl2lds16(const void* g, void* l) {
  __builtin_amdgcn_global_load_lds(
      (const __attribute__((address_space(1))) void*)g,
      (__attribute__((address_space(3))) void*)l, 16, 0, 0);
}

// ---------------------------------------------------------------------------
// fp16-split MFMA GEMM: C = epilogue(A @ W (+ bias))
// A as hi/lo f16 [M,K] row-major; W as hi/lo f16 TRANSPOSED [Nn,K].
// acc += ah*bh + ah*bl + al*bh (3 MFMAs ~ fp32 precision).
// BM=BN=128, BK=32, 256 threads (4 waves 2x2), per-wave 4x4 16x16x32 tiles.
// blockIdx.z = split-K part (Kd = per-part K length).
// XCD swizzle: when gridDim.x%8==0, blocks on one XCD share a contiguous
// n-column group so B-tiles stay resident in that XCD's 4MB L2.
// mode 0: Cf = v (+bias)
// mode 1: v = gelu(v+bias); write halves Oh/Ol
// mode 5: atomicAdd(Cf, v)   (no bias; split-K accumulate)
// mode 6: write halves Oh/Ol (no activation)
// mode 7: u = Uh[idx]+Ul[idx]; v = silu(u)*v; write halves (may alias U)
// ---------------------------------------------------------------------------
__global__ __launch_bounds__(256) void mfma_gemm(
    const _Float16* __restrict__ Ah, const _Float16* __restrict__ Al, int lda,
    const _Float16* __restrict__ Bh, const _Float16* __restrict__ Bl, int ldb,
    int Bn,
    const float* __restrict__ bias,
    float* __restrict__ Cf, _Float16* __restrict__ Oh, _Float16* __restrict__ Ol,
    int ldc,
    const _Float16* __restrict__ Uh, const _Float16* __restrict__ Ul,
    int Kd, int mode)
{
  __shared__ _Float16 smem[16384];           // 32 KB
  _Float16* sAh = smem;
  _Float16* sAl = smem + 4096;
  _Float16* sBh = smem + 8192;
  _Float16* sBl = smem + 12288;

  const int tid = threadIdx.x;

  // ---- XCD-aware swizzle (bid%8 == XCD on MI355X round-robin dispatch)
  int bx, by;
  {
    const int gx = gridDim.x;
    if ((gx & 7) == 0) {
      int bid = blockIdx.y * gx + blockIdx.x;
      int npx = gx >> 3;
      int xcd = bid & 7, slot = bid >> 3;
      bx = xcd * npx + slot % npx;
      by = slot / npx;
    } else {
      bx = blockIdx.x; by = blockIdx.y;
    }
  }
  const int m0 = by * 128, n0 = bx * 128;
  const int kbeg = blockIdx.z * Kd;

  const int q0 = tid, q1 = tid + 256;
  const int r0 = q0 >> 2, r1 = q1 >> 2;
  const int cg0 = (q0 & 3) ^ ((r0 >> 1) & 3);
  const int cg1 = (q1 & 3) ^ ((r1 >> 1) & 3);
  int br0 = n0 + r0; if (br0 >= Bn) br0 = Bn - 1;
  int br1 = n0 + r1; if (br1 >= Bn) br1 = Bn - 1;
  const _Float16* gA0h = Ah + (size_t)(m0 + r0) * lda + kbeg + cg0 * 8;
  const _Float16* gA1h = Ah + (size_t)(m0 + r1) * lda + kbeg + cg1 * 8;
  const _Float16* gA0l = Al + (size_t)(m0 + r0) * lda + kbeg + cg0 * 8;
  const _Float16* gA1l = Al + (size_t)(m0 + r1) * lda + kbeg + cg1 * 8;
  const _Float16* gB0h = Bh + (size_t)br0 * ldb + kbeg + cg0 * 8;
  const _Float16* gB1h = Bh + (size_t)br1 * ldb + kbeg + cg1 * 8;
  const _Float16* gB0l = Bl + (size_t)br0 * ldb + kbeg + cg0 * 8;
  const _Float16* gB1l = Bl + (size_t)br1 * ldb + kbeg + cg1 * 8;

  const int lane = tid & 63;
  const int wave = tid >> 6;
  const int wm = (wave >> 1) * 64, wn = (wave & 1) * 64;
  const int fr = lane & 15, quad = lane >> 4;
  int aoff[4], boff[4];
#pragma unroll
  for (int t = 0; t < 4; ++t) {
    int ar = wm + t * 16 + fr;
    aoff[t] = ar * 32 + (quad ^ ((ar >> 1) & 3)) * 8;
    int brr = wn + t * 16 + fr;
    boff[t] = brr * 32 + (quad ^ ((brr >> 1) & 3)) * 8;
  }

  floatx4 acc[4][4];
#pragma unroll
  for (int i = 0; i < 4; ++i)
#pragma unroll
    for (int j = 0; j < 4; ++j) {
      floatx4 z = {0.f, 0.f, 0.f, 0.f};
      acc[i][j] = z;
    }

  for (int k0 = 0; k0 < Kd; k0 += 32) {
    gl2lds16(gA0h, sAh + q0 * 8);
    gl2lds16(gA1h, sAh + q1 * 8);
    gl2lds16(gA0l, sAl + q0 * 8);
    gl2lds16(gA1l, sAl + q1 * 8);
    gl2lds16(gB0h, sBh + q0 * 8);
    gl2lds16(gB1h, sBh + q1 * 8);
    gl2lds16(gB0l, sBl + q0 * 8);
    gl2lds16(gB1l, sBl + q1 * 8);
    gA0h += 32; gA1h += 32; gA0l += 32; gA1l += 32;
    gB0h += 32; gB1h += 32; gB0l += 32; gB1l += 32;
    __syncthreads();

    half8 a_h[4], a_l[4], b_h[4], b_l[4];
#pragma unroll
    for (int t = 0; t < 4; ++t) {
      a_h[t] = *(const half8*)(sAh + aoff[t]);
      a_l[t] = *(const half8*)(sAl + aoff[t]);
      b_h[t] = *(const half8*)(sBh + boff[t]);
      b_l[t] = *(const half8*)(sBl + boff[t]);
    }
#pragma unroll
    for (int i = 0; i < 4; ++i)
#pragma unroll
      for (int j = 0; j < 4; ++j) {
        acc[i][j] = __builtin_amdgcn_mfma_f32_16x16x32_f16(a_h[i], b_h[j], acc[i][j], 0, 0, 0);
        acc[i][j] = __builtin_amdgcn_mfma_f32_16x16x32_f16(a_h[i], b_l[j], acc[i][j], 0, 0, 0);
        acc[i][j] = __builtin_amdgcn_mfma_f32_16x16x32_f16(a_l[i], b_h[j], acc[i][j], 0, 0, 0);
      }
    __syncthreads();
  }

#pragma unroll
  for (int j = 0; j < 4; ++j) {
    int col = n0 + wn + j * 16 + fr;
    if (col < Bn) {
      float bv = bias ? bias[col] : 0.f;
#pragma unroll
      for (int i = 0; i < 4; ++i) {
#pragma unroll
        for (int r = 0; r < 4; ++r) {
          int row = m0 + wm + i * 16 + quad * 4 + r;
          size_t idx = (size_t)row * ldc + col;
          float v = acc[i][j][r] + bv;
          if (mode == 1) {
            v = 0.5f * v * (1.0f + erff(v * 0.70710678118654752440f));
            _Float16 hh = (_Float16)v;
            Oh[idx] = hh; Ol[idx] = (_Float16)(v - (float)hh);
          } else if (mode == 5) {
            atomicAdd(&Cf[idx], v);
          } else if (mode == 6) {
            _Float16 hh = (_Float16)v;
            Oh[idx] = hh; Ol[idx] = (_Float16)(v - (float)hh);
          } else if (mode == 7) {
            float u = (float)Uh[idx] + (float)Ul[idx];
            v = (u / (1.0f + expf(-u))) * v;
            _Float16 hh = (_Float16)v;
            Oh[idx] = hh; Ol[idx] = (_Float16)(v - (float)hh);
          } else {
            Cf[idx] = v;
          }
        }
      }
    }
  }
}

// elementwise fp32 -> (hi,lo) f16 split
__global__ void split_kernel(const float* __restrict__ src,
                             _Float16* __restrict__ h, _Float16* __restrict__ l, int n)
{
  int i = blockIdx.x * 256 + threadIdx.x;
  if (i < n) {
    float v = src[i];
    _Float16 hh = (_Float16)v;
    h[i] = hh;
    l[i] = (_Float16)(v - (float)hh);
  }
}

// W [K][Nn] fp32 -> Wt hi/lo f16 [Nn][K]
__global__ __launch_bounds__(256) void tsplit_kernel(
    const float* __restrict__ W, int K, int Nn,
    _Float16* __restrict__ Th, _Float16* __restrict__ Tl)
{
  __shared__ float tile[32][33];
  int k0 = blockIdx.x * 32, n0 = blockIdx.y * 32;
  int tx = threadIdx.x & 31, ty = threadIdx.x >> 5;
#pragma unroll
  for (int i = 0; i < 32; i += 8)
    tile[ty + i][tx] = W[(size_t)(k0 + ty + i) * Nn + (n0 + tx)];
  __syncthreads();
#pragma unroll
  for (int i = 0; i < 32; i += 8) {
    float v = tile[tx][ty + i];
    _Float16 hh = (_Float16)v;
    size_t idx = (size_t)(n0 + ty + i) * K + (k0 + tx);
    Th[idx] = hh;
    Tl[idx] = (_Float16)(v - (float)hh);
  }
}

// proj_w [1120][8] -> pwt [8][1120]
__global__ void pwt_kernel(const float* __restrict__ pw, float* __restrict__ pwt)
{
  int idx = blockIdx.x * 256 + threadIdx.x;
  if (idx < DG * NE) {
    int e = idx / DG, c = idx % DG;
    pwt[idx] = pw[c * NE + e];
  }
}

__global__ void gi_bias_init_kernel(float* __restrict__ gi, const float* __restrict__ b)
{
  int idx = blockIdx.x * 256 + threadIdx.x;
  if (idx < N_TOK * 64) {
    int row = idx >> 6, col = idx & 63;
    gi[(size_t)row * DG + 1024 + col] = b[col];
  }
}

__global__ void copy_x_kernel(const float* __restrict__ x, float* __restrict__ gi)
{
  int idx = blockIdx.x * 256 + threadIdx.x;
  if (idx < N_TOK * (HD / 4)) {
    int row = idx >> 8;
    int c4  = idx & 255;
    ((float4*)gi)[(size_t)row * (DG / 4) + c4] = ((const float4*)x)[idx];
  }
}

__global__ void pos_kernel(const int* __restrict__ positions,
                           const float* __restrict__ pt, float* __restrict__ gi)
{
  int idx = blockIdx.x * 256 + threadIdx.x;
  if (idx < N_TOK * (POS_D / 4)) {
    int row = idx >> 3;
    int j4  = idx & 7;
    ((float4*)gi)[(size_t)row * (DG / 4) + (1088 / 4) + j4] =
        ((const float4*)pt)[(size_t)positions[row] * 8 + j4];
  }
}

__global__ __launch_bounds__(256) void nctx_kernel(const float* __restrict__ gi,
                                                   float* __restrict__ o_nc)
{
  int b = blockIdx.x / 96, c = blockIdx.x % 96;
  int t = threadIdx.x;
  float s = 0.f;
  for (int srow = t; srow < 2048; srow += 256)
    s += gi[(size_t)(b * 2048 + srow) * DG + 1024 + c];
  for (int off = 32; off; off >>= 1) s += __shfl_xor(s, off, 64);
  __shared__ float red[4];
  if ((t & 63) == 0) red[t >> 6] = s;
  __syncthreads();
  if (t == 0) o_nc[b * 96 + c] = (red[0] + red[1] + red[2] + red[3]) * (1.f / 2048.f);
}

__global__ __launch_bounds__(256) void rmsnorm_kernel(float* __restrict__ gi,
                                                      const float* __restrict__ w,
                                                      _Float16* __restrict__ gih,
                                                      _Float16* __restrict__ gil)
{
  int row = blockIdx.x, t = threadIdx.x;
  float* g = gi + (size_t)row * DG;
  float s = 0.f;
  for (int c = t; c < DG; c += 256) { float v = g[c]; s += v * v; }
  for (int off = 32; off; off >>= 1) s += __shfl_xor(s, off, 64);
  __shared__ float red[4];
  if ((t & 63) == 0) red[t >> 6] = s;
  __syncthreads();
  float tot = red[0] + red[1] + red[2] + red[3];
  float scale = rsqrtf(tot * (1.0f / DG) + 1e-6f);
  for (int c = t; c < DG; c += 256) {
    float v = g[c] * scale * w[c];
    g[c] = v;
    _Float16 hh = (_Float16)v;
    size_t idx = (size_t)row * DG + c;
    gih[idx] = hh;
    gil[idx] = (_Float16)(v - (float)hh);
  }
}

// logits: one wave per token; pwt [8][1120] read coalesced from global (L2-hot).
// key = expert<<45 | w_bits<<14 | (16383-idx)
__global__ __launch_bounds__(64) void logits_kernel(
    const float* __restrict__ h, const float* __restrict__ pwt,
    const float* __restrict__ tptr,
    float* __restrict__ scores, float* __restrict__ o_idx,
    float* __restrict__ o_val, unsigned long long* __restrict__ keys,
    int* __restrict__ fe)
{
  const int row = blockIdx.x;
  const int lane = threadIdx.x;
  const float* hr = h + (size_t)row * DG;

  float acc[NE];
#pragma unroll
  for (int e = 0; e < NE; ++e) acc[e] = 0.f;

#pragma unroll
  for (int it = 0; it < 4; ++it) {
    int c = it * 256 + lane * 4;
    float4 hv = *(const float4*)(hr + c);
#pragma unroll
    for (int e = 0; e < NE; ++e) {
      float4 wv = *(const float4*)(pwt + e * DG + c);
      acc[e] += hv.x * wv.x + hv.y * wv.y + hv.z * wv.z + hv.w * wv.w;
    }
  }
  if (lane < 24) {   // tail: c = 1024 .. 1119
    int c = 1024 + lane * 4;
    float4 hv = *(const float4*)(hr + c);
#pragma unroll
    for (int e = 0; e < NE; ++e) {
      float4 wv = *(const float4*)(pwt + e * DG + c);
      acc[e] += hv.x * wv.x + hv.y * wv.y + hv.z * wv.z + hv.w * wv.w;
    }
  }
#pragma unroll
  for (int e = 0; e < NE; ++e)
    for (int off = 32; off; off >>= 1) acc[e] += __shfl_xor(acc[e], off, 64);

  if (lane == 0) {
    float temp = fmaxf(tptr[0], 0.3f);
    float l[NE];
    float mx = -1e30f;
#pragma unroll
    for (int e = 0; e < NE; ++e) { l[e] = acc[e] / temp; mx = fmaxf(mx, l[e]); }
    float s = 0.f;
#pragma unroll
    for (int e = 0; e < NE; ++e) { l[e] = expf(l[e] - mx); s += l[e]; }
    float inv = 1.f / s;
#pragma unroll
    for (int e = 0; e < NE; ++e) { l[e] *= inv; scores[(size_t)row * NE + e] = l[e]; }
    int i0 = 0;
#pragma unroll
    for (int e = 1; e < NE; ++e) if (l[e] > l[i0]) i0 = e;
    int i1 = -1;
#pragma unroll
    for (int e = 0; e < NE; ++e)
      if (e != i0 && (i1 < 0 || l[e] > l[i1])) i1 = e;
    o_idx[row * 2 + 0] = (float)i0;  o_idx[row * 2 + 1] = (float)i1;
    o_val[row * 2 + 0] = l[i0];      o_val[row * 2 + 1] = l[i1];
    fe[row * 2 + 0] = i0;     fe[row * 2 + 1] = i1;
    unsigned int wb0 = __float_as_uint(l[i0]);
    unsigned int wb1 = __float_as_uint(l[i1]);
    keys[row * 2 + 0] = ((unsigned long long)i0 << 45) |
                        ((unsigned long long)wb0 << 14) |
                        (unsigned long long)(16383 - (row * 2 + 0));
    keys[row * 2 + 1] = ((unsigned long long)i1 << 45) |
                        ((unsigned long long)wb1 << 14) |
                        (unsigned long long)(16383 - (row * 2 + 1));
  }
}

// expert histogram from fe, LDS-local then 8 device atomics per block
__global__ __launch_bounds__(256) void hist_kernel(
    const int* __restrict__ fe, unsigned int* __restrict__ hist)
{
  __shared__ unsigned int lh[NE];
  if (threadIdx.x < NE) lh[threadIdx.x] = 0;
  __syncthreads();
  for (int i = blockIdx.x * 256 + threadIdx.x; i < NK; i += gridDim.x * 256)
    atomicAdd(&lh[fe[i]], 1u);
  __syncthreads();
  if (threadIdx.x < NE) atomicAdd(&hist[threadIdx.x], lh[threadIdx.x]);
}

__global__ void zero_small_kernel(int* __restrict__ ecnt, unsigned int* __restrict__ hist)
{
  if (threadIdx.x < NE) { ecnt[threadIdx.x] = 0; hist[threadIdx.x] = 0; }
}

__global__ void zero_gcnt_kernel(int* __restrict__ gcnt)
{
  int i = blockIdx.x * 256 + threadIdx.x;
  if (i < NK) gcnt[i] = 0;
}

__global__ __launch_bounds__(256) void rank_partial_kernel(
    const unsigned long long* __restrict__ keys, int* __restrict__ gcnt)
{
  __shared__ unsigned long long sk[1024];
  int i = blockIdx.x * 256 + threadIdx.x;
  unsigned long long ki = keys[i];
  int base = blockIdx.y * 1024;
  for (int j = threadIdx.x; j < 1024; j += 256)
    sk[j] = keys[base + j];
  __syncthreads();
  int c = 0;
#pragma unroll 8
  for (int jj = 0; jj < 1024; ++jj)
    c += (sk[jj] > ki) ? 1 : 0;
  atomicAdd(&gcnt[i], c);
}

__global__ __launch_bounds__(256) void rank_finalize_kernel(
    const int* __restrict__ gcnt, const int* __restrict__ fe,
    const unsigned int* __restrict__ hist,
    float* __restrict__ o_asg, float* __restrict__ o_pos, int* __restrict__ ecnt)
{
  int i = blockIdx.x * 256 + threadIdx.x;
  if (i >= NK) return;
  int e = fe[i];
  int suf = 0;
#pragma unroll
  for (int e2 = 0; e2 < NE; ++e2) suf += (e2 > e) ? (int)hist[e2] : 0;
  int rank = gcnt[i] - suf;
  bool assigned = rank < CAP;
  o_asg[i] = assigned ? 1.f : 0.f;
  o_pos[i] = assigned ? (float)rank : 0.f;
  if (assigned) atomicAdd(&ecnt[e], 1);
}

__global__ void overflow_kernel(const float* __restrict__ o_asg, float* __restrict__ o_ovf)
{
  int n = blockIdx.x * 256 + threadIdx.x;
  if (n < N_TOK)
    o_ovf[n] = (o_asg[n * 2] + o_asg[n * 2 + 1] > 0.f) ? 0.f : 1.f;
}

__global__ __launch_bounds__(256) void me_kernel(const float* __restrict__ scores,
                                                 float* __restrict__ me_sum)
{
  int e = blockIdx.x, t = threadIdx.x;
  float s = 0.f;
  for (int r = t; r < N_TOK; r += 256) s += scores[(size_t)r * NE + e];
  for (int off = 32; off; off >>= 1) s += __shfl_xor(s, off, 64);
  __shared__ float red[4];
  if ((t & 63) == 0) red[t >> 6] = s;
  __syncthreads();
  if (t == 0) me_sum[e] = red[0] + red[1] + red[2] + red[3];
}

__global__ void finalize_kernel(const int* __restrict__ ecnt,
                                const float* __restrict__ me_sum,
                                float* __restrict__ o_ec, float* __restrict__ o_aux)
{
  if (threadIdx.x == 0) {
    float aux = 0.f;
    for (int e = 0; e < NE; ++e) {
      float ce = (float)ecnt[e] * (1.f / N_TOK);
      float me = me_sum[e] * (1.f / N_TOK);
      aux += me * ce;
      o_ec[e] = (float)ecnt[e];
    }
    o_aux[0] = 0.01f * 8.f * aux;
  }
}

extern "C" void kernel_launch(void* const* d_in, const int* in_sizes, int n_in,
                              void* d_out, int out_size, void* d_ws, size_t ws_size,
                              hipStream_t stream)
{
  (void)in_sizes; (void)n_in; (void)out_size; (void)ws_size;
  const float* x         = (const float*)d_in[0];
  const int*   positions = (const int*)d_in[1];
  const float* w_c1      = (const float*)d_in[2];
  const float* b_c1      = (const float*)d_in[3];
  const float* w_c2      = (const float*)d_in[4];
  const float* b_c2      = (const float*)d_in[5];
  const float* norm_w    = (const float*)d_in[6];
  const float* mlp_w1    = (const float*)d_in[7];
  const float* mlp_w3    = (const float*)d_in[8];
  const float* mlp_w2    = (const float*)d_in[9];
  const float* proj_w    = (const float*)d_in[10];
  const float* pos_table = (const float*)d_in[11];
  const float* temperature = (const float*)d_in[12];

  float* out   = (float*)d_out;
  float* o_idx = out;
  float* o_val = out + 16384;
  float* o_asg = out + 32768;
  float* o_pos = out + 49152;
  float* o_ovf = out + 65536;
  float* o_ec  = out + 73728;
  float* o_aux = out + 73736;
  float* o_nc  = out + 73737;

  // ---------- workspace carve (~165.8 MB; 174.6 known-safe) ----------
  char* p = (char*)d_ws;
  auto take = [&](size_t bytes) { char* r = p; p += (bytes + 255) & ~(size_t)255; return r; };

  float*    gi  = (float*)take((size_t)N_TOK * DG * 4);
  _Float16* gih = (_Float16*)take((size_t)N_TOK * DG * 2);
  _Float16* gil = (_Float16*)take((size_t)N_TOK * DG * 2);

  _Float16* WR = (_Float16*)take((size_t)6 * DG * HID * 2);
  _Float16* wc1th = WR;
  _Float16* wc1tl = WR + 2097152;
  _Float16* wc2th = WR + 4194304;
  _Float16* wc2tl = WR + 4325376;
  _Float16* w1th  = WR;
  _Float16* w1tl  = WR + 3440640;
  _Float16* w3th  = WR + 6881280;
  _Float16* w3tl  = WR + 10321920;
  _Float16* w2th  = WR + 13762560;
  _Float16* w2tl  = WR + 17203200;

  char* CR = take((size_t)50331648);
  _Float16* xh   = (_Float16*)CR;                 // ctx phase: 4096x1024
  _Float16* xl   = (_Float16*)(CR + 8388608);
  _Float16* ctxh = (_Float16*)(CR + 16777216);    // 4096x2048
  _Float16* ctxl = (_Float16*)(CR + 33554432);
  _Float16* Xh   = (_Float16*)CR;                 // mlp phase: 4096x3072 halves
  _Float16* Xl   = (_Float16*)(CR + 25165824);

  float* scores = (float*)take((size_t)N_TOK * NE * 4);
  unsigned long long* keys = (unsigned long long*)take((size_t)NK * 8);
  int*   fe     = (int*)take((size_t)NK * 4);
  int*   gcnt   = (int*)take((size_t)NK * 4);
  float* pwt    = (float*)take((size_t)DG * NE * 4);
  int*   ecnt   = (int*)take(256);
  unsigned int* hist = (unsigned int*)take(256);
  float* me_sum = (float*)take(256);

  // ---------- stage 1: gi assembly ----------
  gi_bias_init_kernel<<<(N_TOK * 64 + 255) / 256, 256, 0, stream>>>(gi, b_c2);
  copy_x_kernel<<<(N_TOK * (HD / 4) + 255) / 256, 256, 0, stream>>>(x, gi);
  pos_kernel<<<(N_TOK * (POS_D / 4) + 255) / 256, 256, 0, stream>>>(positions, pos_table, gi);

  // ---------- stage 2: context MLP, 2 chunks of 4096 rows ----------
  tsplit_kernel<<<dim3(HD / 32, CH / 32),   256, 0, stream>>>(w_c1, HD, CH, wc1th, wc1tl);
  tsplit_kernel<<<dim3(CH / 32, CTXD / 32), 256, 0, stream>>>(w_c2, CH, CTXD, wc2th, wc2tl);
  for (int c = 0; c < 2; ++c) {
    size_t base = (size_t)c * 4096;
    split_kernel<<<(4096 * HD + 255) / 256, 256, 0, stream>>>(
        x + base * HD, xh, xl, 4096 * HD);
    mfma_gemm<<<dim3(CH / 128, 4096 / 128), 256, 0, stream>>>(
        xh, xl, HD, wc1th, wc1tl, HD, CH, b_c1,
        nullptr, ctxh, ctxl, CH, nullptr, nullptr, HD, 1);
    mfma_gemm<<<dim3(1, 4096 / 128, 8), 256, 0, stream>>>(
        ctxh, ctxl, CH, wc2th, wc2tl, CH, CTXD, nullptr,
        gi + base * DG + 1024, nullptr, nullptr, DG, nullptr, nullptr, CH / 8, 5);
  }

  // ---------- stage 3: next_context (pre-norm), RMSNorm + halves ----------
  nctx_kernel<<<4 * 96, 256, 0, stream>>>(gi, o_nc);
  rmsnorm_kernel<<<N_TOK, 256, 0, stream>>>(gi, norm_w, gih, gil);

  // ---------- stage 4: SwiGLU MLP, 2 chunks of 4096 rows ----------
  tsplit_kernel<<<dim3(DG / 32, HID / 32), 256, 0, stream>>>(mlp_w1, DG, HID, w1th, w1tl);
  tsplit_kernel<<<dim3(DG / 32, HID / 32), 256, 0, stream>>>(mlp_w3, DG, HID, w3th, w3tl);
  tsplit_kernel<<<dim3(HID / 32, DG / 32), 256, 0, stream>>>(mlp_w2, HID, DG, w2th, w2tl);
  for (int c = 0; c < 2; ++c) {
    size_t base = (size_t)c * 4096;
    const _Float16* ah = gih + base * DG;
    const _Float16* al = gil + base * DG;
    // X = gi@w1 (halves; grid 24x32, XCD-swizzled)
    mfma_gemm<<<dim3(HID / 128, 4096 / 128), 256, 0, stream>>>(
        ah, al, DG, w1th, w1tl, DG, HID, nullptr,
        nullptr, Xh, Xl, HID, nullptr, nullptr, DG, 6);
    // X = silu(X) * (gi@w3)  (in place, halves)
    mfma_gemm<<<dim3(HID / 128, 4096 / 128), 256, 0, stream>>>(
        ah, al, DG, w3th, w3tl, DG, HID, nullptr,
        nullptr, Xh, Xl, HID, Xh, Xl, DG, 7);
    // gi += X @ w2   (split-K=3; grid 9x32x3, no swizzle: gx=9)
    mfma_gemm<<<dim3((DG + 127) / 128, 4096 / 128, 3), 256, 0, stream>>>(
        Xh, Xl, HID, w2th, w2tl, HID, DG, nullptr,
        gi + base * DG, nullptr, nullptr, DG, nullptr, nullptr, HID / 3, 5);
  }

  // ---------- stage 5: router (h == gi) ----------
  pwt_kernel<<<(DG * NE + 255) / 256, 256, 0, stream>>>(proj_w, pwt);
  zero_small_kernel<<<1, 64, 0, stream>>>(ecnt, hist);
  zero_gcnt_kernel<<<NK / 256, 256, 0, stream>>>(gcnt);
  logits_kernel<<<N_TOK, 64, 0, stream>>>(gi, pwt, temperature,
                                          scores, o_idx, o_val, keys, fe);
  hist_kernel<<<16, 256, 0, stream>>>(fe, hist);
  rank_partial_kernel<<<dim3(NK / 256, NK / 1024), 256, 0, stream>>>(keys, gcnt);
  rank_finalize_kernel<<<NK / 256, 256, 0, stream>>>(gcnt, fe, hist, o_asg, o_pos, ecnt);
  overflow_kernel<<<N_TOK / 256, 256, 0, stream>>>(o_asg, o_ovf);
  me_kernel<<<NE, 256, 0, stream>>>(scores, me_sum);
  finalize_kernel<<<1, 64, 0, stream>>>(ecnt, me_sum, o_ec, o_aux);
}

// Round 10
// 1098.869 us; speedup vs baseline: 1.2656x; 1.2656x over previous
//
#include <hip/hip_runtime.h>
#include <math.h>

#define N_TOK 8192
#define HD    1024
#define CTXD  64
#define POS_D 32
#define DG    1120
#define HID   3072
#define NE    8
#define CAP   2048
#define NK    (N_TOK * 2)
#define CH    2048          // context hidden width (2*H)

typedef _Float16 half8 __attribute__((ext_vector_type(8)));
typedef float    floatx4 __attribute__((ext_vector_type(4)));

__device__ static inline void gl2lds16(const void* g, void* l) {
  __builtin_amdgcn_global_load_lds(
      (const __attribute__((address_space(1))) void*)g,
      (__attribute__((address_space(3))) void*)l, 16, 0, 0);
}

// ---------------------------------------------------------------------------
// fp16-split MFMA GEMM: C = epilogue(A @ W (+ bias))
// A as hi/lo f16 [M,K] row-major; W as hi/lo f16 TRANSPOSED [Nn,K].
// acc += ah*bh + ah*bl + al*bh (3 MFMAs ~ fp32 precision).
// BM=BN=128, BK=32, 256 threads (4 waves 2x2), per-wave 4x4 16x16x32 tiles.
// blockIdx.z = split-K part (Kd = per-part K length).
// mode 0: Cf = v (+bias)
// mode 1: v = gelu(v+bias); write halves Oh/Ol
// mode 5: atomicAdd(Cf, v)   (no bias; split-K accumulate)
// ---------------------------------------------------------------------------
__global__ __launch_bounds__(256) void mfma_gemm(
    const _Float16* __restrict__ Ah, const _Float16* __restrict__ Al, int lda,
    const _Float16* __restrict__ Bh, const _Float16* __restrict__ Bl, int ldb,
    int Bn,
    const float* __restrict__ bias,
    float* __restrict__ Cf, _Float16* __restrict__ Oh, _Float16* __restrict__ Ol,
    int ldc,
    int Kd, int mode)
{
  __shared__ _Float16 smem[16384];           // 32 KB
  _Float16* sAh = smem;
  _Float16* sAl = smem + 4096;
  _Float16* sBh = smem + 8192;
  _Float16* sBl = smem + 12288;

  const int tid = threadIdx.x;
  const int m0 = blockIdx.y * 128, n0 = blockIdx.x * 128;
  const int kbeg = blockIdx.z * Kd;

  const int q0 = tid, q1 = tid + 256;
  const int r0 = q0 >> 2, r1 = q1 >> 2;
  const int cg0 = (q0 & 3) ^ ((r0 >> 1) & 3);
  const int cg1 = (q1 & 3) ^ ((r1 >> 1) & 3);
  int br0 = n0 + r0; if (br0 >= Bn) br0 = Bn - 1;
  int br1 = n0 + r1; if (br1 >= Bn) br1 = Bn - 1;
  const _Float16* gA0h = Ah + (size_t)(m0 + r0) * lda + kbeg + cg0 * 8;
  const _Float16* gA1h = Ah + (size_t)(m0 + r1) * lda + kbeg + cg1 * 8;
  const _Float16* gA0l = Al + (size_t)(m0 + r0) * lda + kbeg + cg0 * 8;
  const _Float16* gA1l = Al + (size_t)(m0 + r1) * lda + kbeg + cg1 * 8;
  const _Float16* gB0h = Bh + (size_t)br0 * ldb + kbeg + cg0 * 8;
  const _Float16* gB1h = Bh + (size_t)br1 * ldb + kbeg + cg1 * 8;
  const _Float16* gB0l = Bl + (size_t)br0 * ldb + kbeg + cg0 * 8;
  const _Float16* gB1l = Bl + (size_t)br1 * ldb + kbeg + cg1 * 8;

  const int lane = tid & 63;
  const int wave = tid >> 6;
  const int wm = (wave >> 1) * 64, wn = (wave & 1) * 64;
  const int fr = lane & 15, quad = lane >> 4;
  int aoff[4], boff[4];
#pragma unroll
  for (int t = 0; t < 4; ++t) {
    int ar = wm + t * 16 + fr;
    aoff[t] = ar * 32 + (quad ^ ((ar >> 1) & 3)) * 8;
    int brr = wn + t * 16 + fr;
    boff[t] = brr * 32 + (quad ^ ((brr >> 1) & 3)) * 8;
  }

  floatx4 acc[4][4];
#pragma unroll
  for (int i = 0; i < 4; ++i)
#pragma unroll
    for (int j = 0; j < 4; ++j) {
      floatx4 z = {0.f, 0.f, 0.f, 0.f};
      acc[i][j] = z;
    }

  for (int k0 = 0; k0 < Kd; k0 += 32) {
    gl2lds16(gA0h, sAh + q0 * 8);
    gl2lds16(gA1h, sAh + q1 * 8);
    gl2lds16(gA0l, sAl + q0 * 8);
    gl2lds16(gA1l, sAl + q1 * 8);
    gl2lds16(gB0h, sBh + q0 * 8);
    gl2lds16(gB1h, sBh + q1 * 8);
    gl2lds16(gB0l, sBl + q0 * 8);
    gl2lds16(gB1l, sBl + q1 * 8);
    gA0h += 32; gA1h += 32; gA0l += 32; gA1l += 32;
    gB0h += 32; gB1h += 32; gB0l += 32; gB1l += 32;
    __syncthreads();

    half8 a_h[4], a_l[4], b_h[4], b_l[4];
#pragma unroll
    for (int t = 0; t < 4; ++t) {
      a_h[t] = *(const half8*)(sAh + aoff[t]);
      a_l[t] = *(const half8*)(sAl + aoff[t]);
      b_h[t] = *(const half8*)(sBh + boff[t]);
      b_l[t] = *(const half8*)(sBl + boff[t]);
    }
#pragma unroll
    for (int i = 0; i < 4; ++i)
#pragma unroll
      for (int j = 0; j < 4; ++j) {
        acc[i][j] = __builtin_amdgcn_mfma_f32_16x16x32_f16(a_h[i], b_h[j], acc[i][j], 0, 0, 0);
        acc[i][j] = __builtin_amdgcn_mfma_f32_16x16x32_f16(a_h[i], b_l[j], acc[i][j], 0, 0, 0);
        acc[i][j] = __builtin_amdgcn_mfma_f32_16x16x32_f16(a_l[i], b_h[j], acc[i][j], 0, 0, 0);
      }
    __syncthreads();
  }

#pragma unroll
  for (int j = 0; j < 4; ++j) {
    int col = n0 + wn + j * 16 + fr;
    if (col < Bn) {
      float bv = bias ? bias[col] : 0.f;
#pragma unroll
      for (int i = 0; i < 4; ++i) {
#pragma unroll
        for (int r = 0; r < 4; ++r) {
          int row = m0 + wm + i * 16 + quad * 4 + r;
          size_t idx = (size_t)row * ldc + col;
          float v = acc[i][j][r] + bv;
          if (mode == 1) {
            v = 0.5f * v * (1.0f + erff(v * 0.70710678118654752440f));
            _Float16 hh = (_Float16)v;
            Oh[idx] = hh; Ol[idx] = (_Float16)(v - (float)hh);
          } else if (mode == 5) {
            atomicAdd(&Cf[idx], v);
          } else {
            Cf[idx] = v;
          }
        }
      }
    }
  }
}

// ---------------------------------------------------------------------------
// Fused SwiGLU up-projection, BN=64: O = silu(A@W1) * (A@W3), halves out.
// BM=128, BN=64, BK=32, 256 threads (4 waves 2m x 2n), per-wave 4x2 tiles
// per accumulator. acc total = 64 VGPRs (same as plain GEMM) -> 3 waves/SIMD.
// LDS: A 16KB + B1 8KB + B2 8KB = 32 KB.
// ---------------------------------------------------------------------------
__global__ __launch_bounds__(256, 3) void mfma_swiglu64(
    const _Float16* __restrict__ Ah, const _Float16* __restrict__ Al, int lda,
    const _Float16* __restrict__ B1h, const _Float16* __restrict__ B1l,
    const _Float16* __restrict__ B2h, const _Float16* __restrict__ B2l, int ldb,
    _Float16* __restrict__ Oh, _Float16* __restrict__ Ol, int ldc,
    int Kd)
{
  __shared__ _Float16 smem[16384];           // 32 KB
  _Float16* sAh  = smem;                     // 128x32
  _Float16* sAl  = smem + 4096;
  _Float16* sB1h = smem + 8192;              // 64x32
  _Float16* sB1l = smem + 10240;
  _Float16* sB2h = smem + 12288;
  _Float16* sB2l = smem + 14336;

  const int tid = threadIdx.x;
  const int m0 = blockIdx.y * 128, n0 = blockIdx.x * 64;

  // A staging: 512 chunks, 2 per thread
  const int q0 = tid, q1 = tid + 256;
  const int ra0 = q0 >> 2, ra1 = q1 >> 2;
  const int ca0 = (q0 & 3) ^ ((ra0 >> 1) & 3);
  const int ca1 = (q1 & 3) ^ ((ra1 >> 1) & 3);
  const _Float16* gA0h = Ah + (size_t)(m0 + ra0) * lda + ca0 * 8;
  const _Float16* gA1h = Ah + (size_t)(m0 + ra1) * lda + ca1 * 8;
  const _Float16* gA0l = Al + (size_t)(m0 + ra0) * lda + ca0 * 8;
  const _Float16* gA1l = Al + (size_t)(m0 + ra1) * lda + ca1 * 8;
  // B staging: 256 chunks, 1 per thread per array
  const int rb = tid >> 2;
  const int cb = (tid & 3) ^ ((rb >> 1) & 3);
  const _Float16* gB1hp = B1h + (size_t)(n0 + rb) * ldb + cb * 8;
  const _Float16* gB1lp = B1l + (size_t)(n0 + rb) * ldb + cb * 8;
  const _Float16* gB2hp = B2h + (size_t)(n0 + rb) * ldb + cb * 8;
  const _Float16* gB2lp = B2l + (size_t)(n0 + rb) * ldb + cb * 8;

  const int lane = tid & 63;
  const int wave = tid >> 6;
  const int wm = (wave >> 1) * 64, wn = (wave & 1) * 32;
  const int fr = lane & 15, quad = lane >> 4;
  int aoff[4], boff[2];
#pragma unroll
  for (int t = 0; t < 4; ++t) {
    int ar = wm + t * 16 + fr;
    aoff[t] = ar * 32 + (quad ^ ((ar >> 1) & 3)) * 8;
  }
#pragma unroll
  for (int t = 0; t < 2; ++t) {
    int brr = wn + t * 16 + fr;
    boff[t] = brr * 32 + (quad ^ ((brr >> 1) & 3)) * 8;
  }

  floatx4 acc1[4][2], acc2[4][2];
#pragma unroll
  for (int i = 0; i < 4; ++i)
#pragma unroll
    for (int j = 0; j < 2; ++j) {
      floatx4 z = {0.f, 0.f, 0.f, 0.f};
      acc1[i][j] = z; acc2[i][j] = z;
    }

  for (int k0 = 0; k0 < Kd; k0 += 32) {
    gl2lds16(gA0h, sAh + q0 * 8);
    gl2lds16(gA1h, sAh + q1 * 8);
    gl2lds16(gA0l, sAl + q0 * 8);
    gl2lds16(gA1l, sAl + q1 * 8);
    gl2lds16(gB1hp, sB1h + tid * 8);
    gl2lds16(gB1lp, sB1l + tid * 8);
    gl2lds16(gB2hp, sB2h + tid * 8);
    gl2lds16(gB2lp, sB2l + tid * 8);
    gA0h += 32; gA1h += 32; gA0l += 32; gA1l += 32;
    gB1hp += 32; gB1lp += 32; gB2hp += 32; gB2lp += 32;
    __syncthreads();

    half8 a_h[4], a_l[4], b_h[2], b_l[2];
#pragma unroll
    for (int t = 0; t < 4; ++t) {
      a_h[t] = *(const half8*)(sAh + aoff[t]);
      a_l[t] = *(const half8*)(sAl + aoff[t]);
    }
#pragma unroll
    for (int t = 0; t < 2; ++t) {
      b_h[t] = *(const half8*)(sB1h + boff[t]);
      b_l[t] = *(const half8*)(sB1l + boff[t]);
    }
#pragma unroll
    for (int i = 0; i < 4; ++i)
#pragma unroll
      for (int j = 0; j < 2; ++j) {
        acc1[i][j] = __builtin_amdgcn_mfma_f32_16x16x32_f16(a_h[i], b_h[j], acc1[i][j], 0, 0, 0);
        acc1[i][j] = __builtin_amdgcn_mfma_f32_16x16x32_f16(a_h[i], b_l[j], acc1[i][j], 0, 0, 0);
        acc1[i][j] = __builtin_amdgcn_mfma_f32_16x16x32_f16(a_l[i], b_h[j], acc1[i][j], 0, 0, 0);
      }
#pragma unroll
    for (int t = 0; t < 2; ++t) {
      b_h[t] = *(const half8*)(sB2h + boff[t]);
      b_l[t] = *(const half8*)(sB2l + boff[t]);
    }
#pragma unroll
    for (int i = 0; i < 4; ++i)
#pragma unroll
      for (int j = 0; j < 2; ++j) {
        acc2[i][j] = __builtin_amdgcn_mfma_f32_16x16x32_f16(a_h[i], b_h[j], acc2[i][j], 0, 0, 0);
        acc2[i][j] = __builtin_amdgcn_mfma_f32_16x16x32_f16(a_h[i], b_l[j], acc2[i][j], 0, 0, 0);
        acc2[i][j] = __builtin_amdgcn_mfma_f32_16x16x32_f16(a_l[i], b_h[j], acc2[i][j], 0, 0, 0);
      }
    __syncthreads();
  }

#pragma unroll
  for (int j = 0; j < 2; ++j) {
    int col = n0 + wn + j * 16 + fr;
#pragma unroll
    for (int i = 0; i < 4; ++i) {
#pragma unroll
      for (int r = 0; r < 4; ++r) {
        int row = m0 + wm + i * 16 + quad * 4 + r;
        size_t idx = (size_t)row * ldc + col;
        float uu = acc1[i][j][r];
        float v = (uu / (1.0f + expf(-uu))) * acc2[i][j][r];
        _Float16 hh = (_Float16)v;
        Oh[idx] = hh; Ol[idx] = (_Float16)(v - (float)hh);
      }
    }
  }
}

// elementwise fp32 -> (hi,lo) f16 split
__global__ void split_kernel(const float* __restrict__ src,
                             _Float16* __restrict__ h, _Float16* __restrict__ l, int n)
{
  int i = blockIdx.x * 256 + threadIdx.x;
  if (i < n) {
    float v = src[i];
    _Float16 hh = (_Float16)v;
    h[i] = hh;
    l[i] = (_Float16)(v - (float)hh);
  }
}

// W [K][Nn] fp32 -> Wt hi/lo f16 [Nn][K]
__global__ __launch_bounds__(256) void tsplit_kernel(
    const float* __restrict__ W, int K, int Nn,
    _Float16* __restrict__ Th, _Float16* __restrict__ Tl)
{
  __shared__ float tile[32][33];
  int k0 = blockIdx.x * 32, n0 = blockIdx.y * 32;
  int tx = threadIdx.x & 31, ty = threadIdx.x >> 5;
#pragma unroll
  for (int i = 0; i < 32; i += 8)
    tile[ty + i][tx] = W[(size_t)(k0 + ty + i) * Nn + (n0 + tx)];
  __syncthreads();
#pragma unroll
  for (int i = 0; i < 32; i += 8) {
    float v = tile[tx][ty + i];
    _Float16 hh = (_Float16)v;
    size_t idx = (size_t)(n0 + ty + i) * K + (k0 + tx);
    Th[idx] = hh;
    Tl[idx] = (_Float16)(v - (float)hh);
  }
}

// proj_w [1120][8] -> pwt [8][1120]
__global__ void pwt_kernel(const float* __restrict__ pw, float* __restrict__ pwt)
{
  int idx = blockIdx.x * 256 + threadIdx.x;
  if (idx < DG * NE) {
    int e = idx / DG, c = idx % DG;
    pwt[idx] = pw[c * NE + e];
  }
}

__global__ void gi_bias_init_kernel(float* __restrict__ gi, const float* __restrict__ b)
{
  int idx = blockIdx.x * 256 + threadIdx.x;
  if (idx < N_TOK * 64) {
    int row = idx >> 6, col = idx & 63;
    gi[(size_t)row * DG + 1024 + col] = b[col];
  }
}

__global__ void copy_x_kernel(const float* __restrict__ x, float* __restrict__ gi)
{
  int idx = blockIdx.x * 256 + threadIdx.x;
  if (idx < N_TOK * (HD / 4)) {
    int row = idx >> 8;
    int c4  = idx & 255;
    ((float4*)gi)[(size_t)row * (DG / 4) + c4] = ((const float4*)x)[idx];
  }
}

__global__ void pos_kernel(const int* __restrict__ positions,
                           const float* __restrict__ pt, float* __restrict__ gi)
{
  int idx = blockIdx.x * 256 + threadIdx.x;
  if (idx < N_TOK * (POS_D / 4)) {
    int row = idx >> 3;
    int j4  = idx & 7;
    ((float4*)gi)[(size_t)row * (DG / 4) + (1088 / 4) + j4] =
        ((const float4*)pt)[(size_t)positions[row] * 8 + j4];
  }
}

__global__ __launch_bounds__(256) void nctx_kernel(const float* __restrict__ gi,
                                                   float* __restrict__ o_nc)
{
  int b = blockIdx.x / 96, c = blockIdx.x % 96;
  int t = threadIdx.x;
  float s = 0.f;
  for (int srow = t; srow < 2048; srow += 256)
    s += gi[(size_t)(b * 2048 + srow) * DG + 1024 + c];
  for (int off = 32; off; off >>= 1) s += __shfl_xor(s, off, 64);
  __shared__ float red[4];
  if ((t & 63) == 0) red[t >> 6] = s;
  __syncthreads();
  if (t == 0) o_nc[b * 96 + c] = (red[0] + red[1] + red[2] + red[3]) * (1.f / 2048.f);
}

__global__ __launch_bounds__(256) void rmsnorm_kernel(float* __restrict__ gi,
                                                      const float* __restrict__ w,
                                                      _Float16* __restrict__ gih,
                                                      _Float16* __restrict__ gil)
{
  int row = blockIdx.x, t = threadIdx.x;
  float* g = gi + (size_t)row * DG;
  float s = 0.f;
  for (int c = t; c < DG; c += 256) { float v = g[c]; s += v * v; }
  for (int off = 32; off; off >>= 1) s += __shfl_xor(s, off, 64);
  __shared__ float red[4];
  if ((t & 63) == 0) red[t >> 6] = s;
  __syncthreads();
  float tot = red[0] + red[1] + red[2] + red[3];
  float scale = rsqrtf(tot * (1.0f / DG) + 1e-6f);
  for (int c = t; c < DG; c += 256) {
    float v = g[c] * scale * w[c];
    g[c] = v;
    _Float16 hh = (_Float16)v;
    size_t idx = (size_t)row * DG + c;
    gih[idx] = hh;
    gil[idx] = (_Float16)(v - (float)hh);
  }
}

// logits: one wave per token; pwt [8][1120] read coalesced from global (L2-hot).
// key = expert<<45 | w_bits<<14 | (16383-idx)
__global__ __launch_bounds__(64) void logits_kernel(
    const float* __restrict__ h, const float* __restrict__ pwt,
    const float* __restrict__ tptr,
    float* __restrict__ scores, float* __restrict__ o_idx,
    float* __restrict__ o_val, unsigned long long* __restrict__ keys,
    int* __restrict__ fe)
{
  const int row = blockIdx.x;
  const int lane = threadIdx.x;
  const float* hr = h + (size_t)row * DG;

  float acc[NE];
#pragma unroll
  for (int e = 0; e < NE; ++e) acc[e] = 0.f;

#pragma unroll
  for (int it = 0; it < 4; ++it) {
    int c = it * 256 + lane * 4;
    float4 hv = *(const float4*)(hr + c);
#pragma unroll
    for (int e = 0; e < NE; ++e) {
      float4 wv = *(const float4*)(pwt + e * DG + c);
      acc[e] += hv.x * wv.x + hv.y * wv.y + hv.z * wv.z + hv.w * wv.w;
    }
  }
  if (lane < 24) {   // tail: c = 1024 .. 1119
    int c = 1024 + lane * 4;
    float4 hv = *(const float4*)(hr + c);
#pragma unroll
    for (int e = 0; e < NE; ++e) {
      float4 wv = *(const float4*)(pwt + e * DG + c);
      acc[e] += hv.x * wv.x + hv.y * wv.y + hv.z * wv.z + hv.w * wv.w;
    }
  }
#pragma unroll
  for (int e = 0; e < NE; ++e)
    for (int off = 32; off; off >>= 1) acc[e] += __shfl_xor(acc[e], off, 64);

  if (lane == 0) {
    float temp = fmaxf(tptr[0], 0.3f);
    float l[NE];
    float mx = -1e30f;
#pragma unroll
    for (int e = 0; e < NE; ++e) { l[e] = acc[e] / temp; mx = fmaxf(mx, l[e]); }
    float s = 0.f;
#pragma unroll
    for (int e = 0; e < NE; ++e) { l[e] = expf(l[e] - mx); s += l[e]; }
    float inv = 1.f / s;
#pragma unroll
    for (int e = 0; e < NE; ++e) { l[e] *= inv; scores[(size_t)row * NE + e] = l[e]; }
    int i0 = 0;
#pragma unroll
    for (int e = 1; e < NE; ++e) if (l[e] > l[i0]) i0 = e;
    int i1 = -1;
#pragma unroll
    for (int e = 0; e < NE; ++e)
      if (e != i0 && (i1 < 0 || l[e] > l[i1])) i1 = e;
    o_idx[row * 2 + 0] = (float)i0;  o_idx[row * 2 + 1] = (float)i1;
    o_val[row * 2 + 0] = l[i0];      o_val[row * 2 + 1] = l[i1];
    fe[row * 2 + 0] = i0;     fe[row * 2 + 1] = i1;
    unsigned int wb0 = __float_as_uint(l[i0]);
    unsigned int wb1 = __float_as_uint(l[i1]);
    keys[row * 2 + 0] = ((unsigned long long)i0 << 45) |
                        ((unsigned long long)wb0 << 14) |
                        (unsigned long long)(16383 - (row * 2 + 0));
    keys[row * 2 + 1] = ((unsigned long long)i1 << 45) |
                        ((unsigned long long)wb1 << 14) |
                        (unsigned long long)(16383 - (row * 2 + 1));
  }
}

// expert histogram from fe, LDS-local then 8 device atomics per block
__global__ __launch_bounds__(256) void hist_kernel(
    const int* __restrict__ fe, unsigned int* __restrict__ hist)
{
  __shared__ unsigned int lh[NE];
  if (threadIdx.x < NE) lh[threadIdx.x] = 0;
  __syncthreads();
  for (int i = blockIdx.x * 256 + threadIdx.x; i < NK; i += gridDim.x * 256)
    atomicAdd(&lh[fe[i]], 1u);
  __syncthreads();
  if (threadIdx.x < NE) atomicAdd(&hist[threadIdx.x], lh[threadIdx.x]);
}

__global__ void zero_small_kernel(int* __restrict__ ecnt, unsigned int* __restrict__ hist)
{
  if (threadIdx.x < NE) { ecnt[threadIdx.x] = 0; hist[threadIdx.x] = 0; }
}

__global__ void zero_gcnt_kernel(int* __restrict__ gcnt)
{
  int i = blockIdx.x * 256 + threadIdx.x;
  if (i < NK) gcnt[i] = 0;
}

__global__ __launch_bounds__(256) void rank_partial_kernel(
    const unsigned long long* __restrict__ keys, int* __restrict__ gcnt)
{
  __shared__ unsigned long long sk[1024];
  int i = blockIdx.x * 256 + threadIdx.x;
  unsigned long long ki = keys[i];
  int base = blockIdx.y * 1024;
  for (int j = threadIdx.x; j < 1024; j += 256)
    sk[j] = keys[base + j];
  __syncthreads();
  int c = 0;
#pragma unroll 8
  for (int jj = 0; jj < 1024; ++jj)
    c += (sk[jj] > ki) ? 1 : 0;
  atomicAdd(&gcnt[i], c);
}

__global__ __launch_bounds__(256) void rank_finalize_kernel(
    const int* __restrict__ gcnt, const int* __restrict__ fe,
    const unsigned int* __restrict__ hist,
    float* __restrict__ o_asg, float* __restrict__ o_pos, int* __restrict__ ecnt)
{
  int i = blockIdx.x * 256 + threadIdx.x;
  if (i >= NK) return;
  int e = fe[i];
  int suf = 0;
#pragma unroll
  for (int e2 = 0; e2 < NE; ++e2) suf += (e2 > e) ? (int)hist[e2] : 0;
  int rank = gcnt[i] - suf;
  bool assigned = rank < CAP;
  o_asg[i] = assigned ? 1.f : 0.f;
  o_pos[i] = assigned ? (float)rank : 0.f;
  if (assigned) atomicAdd(&ecnt[e], 1);
}

__global__ void overflow_kernel(const float* __restrict__ o_asg, float* __restrict__ o_ovf)
{
  int n = blockIdx.x * 256 + threadIdx.x;
  if (n < N_TOK)
    o_ovf[n] = (o_asg[n * 2] + o_asg[n * 2 + 1] > 0.f) ? 0.f : 1.f;
}

__global__ __launch_bounds__(256) void me_kernel(const float* __restrict__ scores,
                                                 float* __restrict__ me_sum)
{
  int e = blockIdx.x, t = threadIdx.x;
  float s = 0.f;
  for (int r = t; r < N_TOK; r += 256) s += scores[(size_t)r * NE + e];
  for (int off = 32; off; off >>= 1) s += __shfl_xor(s, off, 64);
  __shared__ float red[4];
  if ((t & 63) == 0) red[t >> 6] = s;
  __syncthreads();
  if (t == 0) me_sum[e] = red[0] + red[1] + red[2] + red[3];
}

__global__ void finalize_kernel(const int* __restrict__ ecnt,
                                const float* __restrict__ me_sum,
                                float* __restrict__ o_ec, float* __restrict__ o_aux)
{
  if (threadIdx.x == 0) {
    float aux = 0.f;
    for (int e = 0; e < NE; ++e) {
      float ce = (float)ecnt[e] * (1.f / N_TOK);
      float me = me_sum[e] * (1.f / N_TOK);
      aux += me * ce;
      o_ec[e] = (float)ecnt[e];
    }
    o_aux[0] = 0.01f * 8.f * aux;
  }
}

extern "C" void kernel_launch(void* const* d_in, const int* in_sizes, int n_in,
                              void* d_out, int out_size, void* d_ws, size_t ws_size,
                              hipStream_t stream)
{
  (void)in_sizes; (void)n_in; (void)out_size; (void)ws_size;
  const float* x         = (const float*)d_in[0];
  const int*   positions = (const int*)d_in[1];
  const float* w_c1      = (const float*)d_in[2];
  const float* b_c1      = (const float*)d_in[3];
  const float* w_c2      = (const float*)d_in[4];
  const float* b_c2      = (const float*)d_in[5];
  const float* norm_w    = (const float*)d_in[6];
  const float* mlp_w1    = (const float*)d_in[7];
  const float* mlp_w3    = (const float*)d_in[8];
  const float* mlp_w2    = (const float*)d_in[9];
  const float* proj_w    = (const float*)d_in[10];
  const float* pos_table = (const float*)d_in[11];
  const float* temperature = (const float*)d_in[12];

  float* out   = (float*)d_out;
  float* o_idx = out;
  float* o_val = out + 16384;
  float* o_asg = out + 32768;
  float* o_pos = out + 49152;
  float* o_ovf = out + 65536;
  float* o_ec  = out + 73728;
  float* o_aux = out + 73736;
  float* o_nc  = out + 73737;

  // ---------- workspace carve (~165.8 MB; 174.6 known-safe) ----------
  char* p = (char*)d_ws;
  auto take = [&](size_t bytes) { char* r = p; p += (bytes + 255) & ~(size_t)255; return r; };

  float*    gi  = (float*)take((size_t)N_TOK * DG * 4);
  _Float16* gih = (_Float16*)take((size_t)N_TOK * DG * 2);
  _Float16* gil = (_Float16*)take((size_t)N_TOK * DG * 2);

  _Float16* WR = (_Float16*)take((size_t)6 * DG * HID * 2);
  _Float16* wc1th = WR;
  _Float16* wc1tl = WR + 2097152;
  _Float16* wc2th = WR + 4194304;
  _Float16* wc2tl = WR + 4325376;
  _Float16* w1th  = WR;
  _Float16* w1tl  = WR + 3440640;
  _Float16* w3th  = WR + 6881280;
  _Float16* w3tl  = WR + 10321920;
  _Float16* w2th  = WR + 13762560;
  _Float16* w2tl  = WR + 17203200;

  char* CR = take((size_t)50331648);
  _Float16* xh   = (_Float16*)CR;                 // ctx phase: 4096x1024
  _Float16* xl   = (_Float16*)(CR + 8388608);
  _Float16* ctxh = (_Float16*)(CR + 16777216);    // 4096x2048
  _Float16* ctxl = (_Float16*)(CR + 33554432);
  _Float16* Xh   = (_Float16*)CR;                 // mlp phase: 4096x3072 halves
  _Float16* Xl   = (_Float16*)(CR + 25165824);

  float* scores = (float*)take((size_t)N_TOK * NE * 4);
  unsigned long long* keys = (unsigned long long*)take((size_t)NK * 8);
  int*   fe     = (int*)take((size_t)NK * 4);
  int*   gcnt   = (int*)take((size_t)NK * 4);
  float* pwt    = (float*)take((size_t)DG * NE * 4);
  int*   ecnt   = (int*)take(256);
  unsigned int* hist = (unsigned int*)take(256);
  float* me_sum = (float*)take(256);

  // ---------- stage 1: gi assembly ----------
  gi_bias_init_kernel<<<(N_TOK * 64 + 255) / 256, 256, 0, stream>>>(gi, b_c2);
  copy_x_kernel<<<(N_TOK * (HD / 4) + 255) / 256, 256, 0, stream>>>(x, gi);
  pos_kernel<<<(N_TOK * (POS_D / 4) + 255) / 256, 256, 0, stream>>>(positions, pos_table, gi);

  // ---------- stage 2: context MLP, 2 chunks of 4096 rows ----------
  tsplit_kernel<<<dim3(HD / 32, CH / 32),   256, 0, stream>>>(w_c1, HD, CH, wc1th, wc1tl);
  tsplit_kernel<<<dim3(CH / 32, CTXD / 32), 256, 0, stream>>>(w_c2, CH, CTXD, wc2th, wc2tl);
  for (int c = 0; c < 2; ++c) {
    size_t base = (size_t)c * 4096;
    split_kernel<<<(4096 * HD + 255) / 256, 256, 0, stream>>>(
        x + base * HD, xh, xl, 4096 * HD);
    mfma_gemm<<<dim3(CH / 128, 4096 / 128), 256, 0, stream>>>(
        xh, xl, HD, wc1th, wc1tl, HD, CH, b_c1,
        nullptr, ctxh, ctxl, CH, HD, 1);
    mfma_gemm<<<dim3(1, 4096 / 128, 8), 256, 0, stream>>>(
        ctxh, ctxl, CH, wc2th, wc2tl, CH, CTXD, nullptr,
        gi + base * DG + 1024, nullptr, nullptr, DG, CH / 8, 5);
  }

  // ---------- stage 3: next_context (pre-norm), RMSNorm + halves ----------
  nctx_kernel<<<4 * 96, 256, 0, stream>>>(gi, o_nc);
  rmsnorm_kernel<<<N_TOK, 256, 0, stream>>>(gi, norm_w, gih, gil);

  // ---------- stage 4: SwiGLU MLP, 2 chunks of 4096 rows (fused BN=64) ----------
  tsplit_kernel<<<dim3(DG / 32, HID / 32), 256, 0, stream>>>(mlp_w1, DG, HID, w1th, w1tl);
  tsplit_kernel<<<dim3(DG / 32, HID / 32), 256, 0, stream>>>(mlp_w3, DG, HID, w3th, w3tl);
  tsplit_kernel<<<dim3(HID / 32, DG / 32), 256, 0, stream>>>(mlp_w2, HID, DG, w2th, w2tl);
  for (int c = 0; c < 2; ++c) {
    size_t base = (size_t)c * 4096;
    const _Float16* ah = gih + base * DG;
    const _Float16* al = gil + base * DG;
    // X = silu(gi@w1) * (gi@w3) -> halves (fused; grid 48x32 = 1536 blocks)
    mfma_swiglu64<<<dim3(HID / 64, 4096 / 128), 256, 0, stream>>>(
        ah, al, DG, w1th, w1tl, w3th, w3tl, DG, Xh, Xl, HID, DG);
    // gi += X @ w2   (split-K=3; grid 9x32x3 = 864 blocks)
    mfma_gemm<<<dim3((DG + 127) / 128, 4096 / 128, 3), 256, 0, stream>>>(
        Xh, Xl, HID, w2th, w2tl, HID, DG, nullptr,
        gi + base * DG, nullptr, nullptr, DG, HID / 3, 5);
  }

  // ---------- stage 5: router (h == gi) ----------
  pwt_kernel<<<(DG * NE + 255) / 256, 256, 0, stream>>>(proj_w, pwt);
  zero_small_kernel<<<1, 64, 0, stream>>>(ecnt, hist);
  zero_gcnt_kernel<<<NK / 256, 256, 0, stream>>>(gcnt);
  logits_kernel<<<N_TOK, 64, 0, stream>>>(gi, pwt, temperature,
                                          scores, o_idx, o_val, keys, fe);
  hist_kernel<<<16, 256, 0, stream>>>(fe, hist);
  rank_partial_kernel<<<dim3(NK / 256, NK / 1024), 256, 0, stream>>>(keys, gcnt);
  rank_finalize_kernel<<<NK / 256, 256, 0, stream>>>(gcnt, fe, hist, o_asg, o_pos, ecnt);
  overflow_kernel<<<N_TOK / 256, 256, 0, stream>>>(o_asg, o_ovf);
  me_kernel<<<NE, 256, 0, stream>>>(scores, me_sum);
  finalize_kernel<<<1, 64, 0, stream>>>(ecnt, me_sum, o_ec, o_aux);
}